// Round 2
// baseline (471.466 us; speedup 1.0000x reference)
//
#include <hip/hip_runtime.h>

// GNN layer, fp32 I/O, decomposed:
//   A = nf @ We[:, 0:64]^T        [N,64]  (fp32, ws)
//   B = nf @ We[:, 64:128]^T      [N,64]  (fp32, ws)
//   C[e] = ef[e] @ We[:,128:160]^T  (on the fly in edge kernel)
//   red[d] += leaky(A[s]+B[d]+C[e]);  red[s] += leaky(A[d]+B[s]+C[e])
//   out = leaky(nf @ Wn[:,0:64]^T + red @ Wn[:,64:128]^T)
// Inputs: nf/ef/We/Wn fp32, src/dst int32. Output fp32.

#define LEAKY(x) ((x) > 0.0f ? (x) : 0.01f * (x))

// ---------------- K1: A,B = nf @ [Wsrc|Wdst]^T ----------------
// block 256 = 2 nodes x 128 outputs; weights in 16 float4 VGPRs/thread.
__global__ __launch_bounds__(256) void node_transform_kernel(
    const float4* __restrict__ nf4,   // N x 16 float4
    const float* __restrict__ We,     // 64 x 160
    float* __restrict__ A, float* __restrict__ B, int N)
{
    __shared__ float4 m_s[2][16];
    const int t = threadIdx.x;
    const int g = t >> 7;     // node slot
    const int j = t & 127;    // combined output index (0..63 -> A, 64..127 -> B)

    float4 w[16];
    {
        const float4* wr = (const float4*)(We + (j & 63) * 160 + ((j < 64) ? 0 : 64));
        #pragma unroll
        for (int k = 0; k < 16; ++k) w[k] = wr[k];
    }

    const int pairs = (N + 1) >> 1;
    for (int q = blockIdx.x; q < pairs; q += gridDim.x) {
        const int n0 = q * 2;
        if (t < 32) {
            int gg = t >> 4, k = t & 15;
            int n = n0 + gg;
            if (n < N) m_s[gg][k] = nf4[(size_t)n * 16 + k];
        }
        __syncthreads();
        const int n = n0 + g;
        if (n < N) {
            float a0 = 0.f, a1 = 0.f, a2 = 0.f, a3 = 0.f;
            #pragma unroll
            for (int k = 0; k < 16; ++k) {
                float4 m = m_s[g][k];
                a0 += m.x * w[k].x;
                a1 += m.y * w[k].y;
                a2 += m.z * w[k].z;
                a3 += m.w * w[k].w;
            }
            float acc = (a0 + a1) + (a2 + a3);
            if (j < 64) A[(size_t)n * 64 + j] = acc;
            else        B[(size_t)n * 64 + (j - 64)] = acc;
        }
        __syncthreads();
    }
}

// ---------------- K2: edge messages + atomic scatter ----------------
// block 256 = 4 edges x 64 channels.
__global__ __launch_bounds__(256) void edge_kernel(
    const float4* __restrict__ ef4,   // E x 8 float4
    const int* __restrict__ src, const int* __restrict__ dst,
    const float* __restrict__ We,
    const float* __restrict__ A, const float* __restrict__ B,
    float* __restrict__ red, int E)
{
    __shared__ float4 ef_s[4][8];
    const int t = threadIdx.x;
    const int i = t >> 6;   // edge slot
    const int o = t & 63;   // output channel

    float4 w[8];
    {
        const float4* wr = (const float4*)(We + o * 160 + 128);
        #pragma unroll
        for (int k = 0; k < 8; ++k) w[k] = wr[k];
    }

    const int quads = (E + 3) >> 2;
    for (int q = blockIdx.x; q < quads; q += gridDim.x) {
        const int e0 = q * 4;
        if (t < 32) {
            int ee = t >> 3, k = t & 7;
            int e = e0 + ee;
            if (e < E) ef_s[ee][k] = ef4[(size_t)e * 8 + k];
        }
        __syncthreads();
        const int e = e0 + i;
        if (e < E) {
            const int s = src[e], d = dst[e];
            float c0 = 0.f, c1 = 0.f, c2 = 0.f, c3 = 0.f;
            #pragma unroll
            for (int k = 0; k < 8; ++k) {
                float4 m = ef_s[i][k];
                c0 += m.x * w[k].x;
                c1 += m.y * w[k].y;
                c2 += m.z * w[k].z;
                c3 += m.w * w[k].w;
            }
            const float c = (c0 + c1) + (c2 + c3);
            const float a_s = A[(size_t)s * 64 + o], b_d = B[(size_t)d * 64 + o];
            const float a_d = A[(size_t)d * 64 + o], b_s = B[(size_t)s * 64 + o];
            float mf = a_s + b_d + c; mf = LEAKY(mf);
            float mr = a_d + b_s + c; mr = LEAKY(mr);
            atomicAdd(&red[(size_t)d * 64 + o], mf);
            atomicAdd(&red[(size_t)s * 64 + o], mr);
        }
        __syncthreads();
    }
}

// ---------------- K3: out = leaky(nf@Wn1^T + red@Wn2^T) ----------------
// block 256 = 4 nodes x 64 channels; 32 float4 weight regs/thread.
__global__ __launch_bounds__(256) void node_out_kernel(
    const float4* __restrict__ nf4,
    const float4* __restrict__ red4,
    const float* __restrict__ Wn,     // 64 x 128
    float* __restrict__ out, int N)
{
    __shared__ float4 m_s[4][32];     // [node][0:16 nf | 16:32 red]
    const int t = threadIdx.x;
    const int g = t >> 6;
    const int o = t & 63;

    float4 w1[16], w2[16];
    {
        const float4* wr = (const float4*)(Wn + o * 128);
        #pragma unroll
        for (int k = 0; k < 16; ++k) w1[k] = wr[k];
        #pragma unroll
        for (int k = 0; k < 16; ++k) w2[k] = wr[16 + k];
    }

    const int groups = (N + 3) >> 2;
    for (int q = blockIdx.x; q < groups; q += gridDim.x) {
        const int n0 = q * 4;
        if (t < 64) {                      // stage nf: 4 nodes x 16 float4
            int gg = t >> 4, k = t & 15;
            int n = n0 + gg;
            if (n < N) m_s[gg][k] = nf4[(size_t)n * 16 + k];
        } else if (t < 128) {              // stage red: 4 nodes x 16 float4
            int tt = t - 64;
            int gg = tt >> 4, k = tt & 15;
            int n = n0 + gg;
            if (n < N) m_s[gg][16 + k] = red4[(size_t)n * 16 + k];
        }
        __syncthreads();
        const int n = n0 + g;
        if (n < N) {
            float a0 = 0.f, a1 = 0.f, a2 = 0.f, a3 = 0.f;
            #pragma unroll
            for (int k = 0; k < 16; ++k) {
                float4 m = m_s[g][k];
                a0 += m.x * w1[k].x;
                a1 += m.y * w1[k].y;
                a2 += m.z * w1[k].z;
                a3 += m.w * w1[k].w;
            }
            #pragma unroll
            for (int k = 0; k < 16; ++k) {
                float4 m = m_s[g][16 + k];
                a0 += m.x * w2[k].x;
                a1 += m.y * w2[k].y;
                a2 += m.z * w2[k].z;
                a3 += m.w * w2[k].w;
            }
            float acc = (a0 + a1) + (a2 + a3);
            out[(size_t)n * 64 + o] = LEAKY(acc);
        }
        __syncthreads();
    }
}

extern "C" void kernel_launch(void* const* d_in, const int* in_sizes, int n_in,
                              void* d_out, int out_size, void* d_ws, size_t ws_size,
                              hipStream_t stream) {
    const float* nf = (const float*)d_in[0];   // [N,64] fp32
    const float* ef = (const float*)d_in[1];   // [E,32] fp32
    const int*   src = (const int*)d_in[2];    // [E] i32
    const int*   dst = (const int*)d_in[3];    // [E] i32
    const float* We = (const float*)d_in[4];   // [64,160] fp32
    const float* Wn = (const float*)d_in[5];   // [64,128] fp32

    const int N = in_sizes[0] / 64;
    const int E = in_sizes[2];

    float* A   = (float*)d_ws;                 // [N,64]
    float* B   = A + (size_t)N * 64;           // [N,64]
    float* red = B + (size_t)N * 64;           // [N,64]

    hipMemsetAsync(red, 0, (size_t)N * 64 * sizeof(float), stream);
    node_transform_kernel<<<2048, 256, 0, stream>>>((const float4*)nf, We, A, B, N);
    edge_kernel<<<4096, 256, 0, stream>>>((const float4*)ef, src, dst, We, A, B, red, E);
    node_out_kernel<<<2048, 256, 0, stream>>>((const float4*)nf, (const float4*)red,
                                              Wn, (float*)d_out, N);
}